// Round 7
// baseline (376.583 us; speedup 1.0000x reference)
//
#include <hip/hip_runtime.h>
#include <hip/hip_bf16.h>
#include <cstdint>

// ---- problem dims ----
#define L_SEQ   2048
#define DM      1024   // d_model
#define DI      2048   // d_inner
#define DXB     512
#define DS      16     // d_state
#define DTR     64     // dt_rank
#define GH      128    // C-heads = DI/DS
#define DP      5184   // 2*DI + 2*DXB + DTR

// zxbcdt column offsets
#define OFF_Z   0
#define OFF_X   2048
#define OFF_B   2560
#define OFF_C   3072
#define OFF_DT  5120

// scan segmentation: 64 segments x 32 steps, 512 blocks (co-resident: 48KB LDS
// -> 3 blocks/CU -> capacity 768 >= 512, so the spin grid-barrier is safe)
#define NSEG    64
#define SEGLEN  32
#define NBLK    512

typedef __bf16 bf16x8 __attribute__((ext_vector_type(8)));
typedef float  f32x4  __attribute__((ext_vector_type(4)));

__device__ __forceinline__ float siluf(float x) {
  return x / (1.f + __expf(-x));
}
__device__ __forceinline__ float softplusf(float x) {
  return x > 20.f ? x : log1pf(__expf(x));
}
__device__ __forceinline__ unsigned short f2bf(float f) {
  union { float f; unsigned u; } v; v.f = f;
  unsigned r = v.u + 0x7fffu + ((v.u >> 16) & 1u);
  return (unsigned short)(r >> 16);
}
__device__ __forceinline__ float bf2f(unsigned short u) {
  union { unsigned u; float f; } v; v.u = ((unsigned)u) << 16;
  return v.f;
}
// async global->LDS, 16B/lane. LDS dest must be wave-uniform base + lane*16.
__device__ __forceinline__ void gload16(const void* g, void* l) {
  __builtin_amdgcn_global_load_lds((const __attribute__((address_space(1))) void*)g,
                                   (__attribute__((address_space(3))) void*)l, 16, 0, 0);
}

// ---------------------------------------------------------------------------
// bf16 MFMA GEMM, 128x128 tile, 256 thr, 4 waves @ 64x64, double-buffered LDS.
// C[M,N](f32) (+)= A[M,K](bf16 row-major) * BT[N,K](bf16)^T
// MODE 0: plain store.
// MODE 1: atomicAdd (split-K via blockIdx.z; only for SMALL outputs — R5
//         showed split-K atomics on a 42 MB output regress 2x).
// MODE 2: bf16 store of softplus(acc + 2*bias[col])   (delta GEMM)
// MODE 3: plain store + bf16 side-write of cols >= OFF_DT into aux (dtr slice)
// ---------------------------------------------------------------------------
template<int MODE>
__global__ __launch_bounds__(256) void mfma_gemm(
    const unsigned short* __restrict__ A,
    const unsigned short* __restrict__ BT,
    float* __restrict__ C, int ldc,
    int N, int K, int ktiles,
    const float* __restrict__ bias,
    unsigned short* __restrict__ aux)
{
  __shared__ __align__(16) unsigned short Asg[2][4096];
  __shared__ __align__(16) unsigned short Bsg[2][4096];

  const int tid  = threadIdx.x;
  const int wave = tid >> 6, lane = tid & 63;
  const int row0 = blockIdx.y * 128;
  const int col0 = blockIdx.x * 128;
  const int kbase = blockIdx.z * ktiles * 32;

  const int s0 = tid, s1 = tid + 256;
  const int rt0 = s0 >> 6, q0 = (s0 >> 4) & 3, m0 = s0 & 15;
  const int rt1 = s1 >> 6, q1 = (s1 >> 4) & 3, m1 = s1 & 15;
  const size_t aoff0 = (size_t)(row0 + rt0 * 16 + m0) * K + q0 * 8 + kbase;
  const size_t aoff1 = (size_t)(row0 + rt1 * 16 + m1) * K + q1 * 8 + kbase;
  int c0i = col0 + rt0 * 16 + m0; if (c0i > N - 1) c0i = N - 1;
  int c1i = col0 + rt1 * 16 + m1; if (c1i > N - 1) c1i = N - 1;
  const size_t boff0 = (size_t)c0i * K + q0 * 8 + kbase;
  const size_t boff1 = (size_t)c1i * K + q1 * 8 + kbase;

  f32x4 acc[4][4];
#pragma unroll
  for (int i = 0; i < 4; ++i)
#pragma unroll
    for (int j = 0; j < 4; ++j) acc[i][j] = (f32x4)0.f;

  const int warow = (wave >> 1) * 4;
  const int wacol = (wave & 1) * 4;

  gload16(A  + aoff0, Asg[0] + s0 * 8);
  gload16(A  + aoff1, Asg[0] + s0 * 8 + 2048);
  gload16(BT + boff0, Bsg[0] + s0 * 8);
  gload16(BT + boff1, Bsg[0] + s0 * 8 + 2048);

  for (int kt = 0; kt < ktiles; ++kt) {
    const int cur = kt & 1;
    __syncthreads();
    if (kt + 1 < ktiles) {
      const int k0 = (kt + 1) * 32;
      gload16(A  + aoff0 + k0, Asg[1 - cur] + s0 * 8);
      gload16(A  + aoff1 + k0, Asg[1 - cur] + s0 * 8 + 2048);
      gload16(BT + boff0 + k0, Bsg[1 - cur] + s0 * 8);
      gload16(BT + boff1 + k0, Bsg[1 - cur] + s0 * 8 + 2048);
    }

    bf16x8 af[4], bfr[4];
#pragma unroll
    for (int i = 0; i < 4; ++i)
      af[i] = *(const bf16x8*)(Asg[cur] + (warow + i) * 512 + lane * 8);
#pragma unroll
    for (int j = 0; j < 4; ++j)
      bfr[j] = *(const bf16x8*)(Bsg[cur] + (wacol + j) * 512 + lane * 8);
#pragma unroll
    for (int i = 0; i < 4; ++i)
#pragma unroll
      for (int j = 0; j < 4; ++j)
        acc[i][j] = __builtin_amdgcn_mfma_f32_16x16x32_bf16(af[i], bfr[j], acc[i][j], 0, 0, 0);
  }

  // epilogue: C/D layout col=lane&15, row=(lane>>4)*4+reg
#pragma unroll
  for (int i = 0; i < 4; ++i) {
    const int rbase = row0 + (warow + i) * 16 + ((lane >> 4) << 2);
#pragma unroll
    for (int j = 0; j < 4; ++j) {
      const int col = col0 + (wacol + j) * 16 + (lane & 15);
      if (col < N) {
#pragma unroll
        for (int r = 0; r < 4; ++r) {
          const float v = acc[i][j][r];
          if (MODE == 0 || MODE == 3) {
            C[(size_t)(rbase + r) * ldc + col] = v;
            if (MODE == 3 && col >= OFF_DT)
              aux[(size_t)(rbase + r) * DTR + (col - OFF_DT)] = f2bf(v);
          } else if (MODE == 1) {
            atomicAdd(C + (size_t)(rbase + r) * ldc + col, v);
          } else {  // MODE 2
            ((unsigned short*)C)[(size_t)(rbase + r) * ldc + col] =
                f2bf(softplusf(v + 2.f * bias[col]));
          }
        }
      }
    }
  }
}

// ---------------------------------------------------------------------------
// prep kernel: range-dispatched fusion of
//   [0,2048)      cast hidden -> Abf (bf16)
//   [2048,7232)   transpose+cast W_in (1024x5184) -> WinT (5184x1024)
//   [7232,7360)   transpose+cast W_dt (64x2048)   -> WdtT (2048x64)
//   [7360,9408)   transpose+cast W_out(2048x1024) -> WoutT(1024x2048)
//   [9408,11456)  zero out (for out-proj split-K atomics)
//   [11456]       zero grid-barrier counters
// ---------------------------------------------------------------------------
__device__ __forceinline__ void tile_transpose(
    const float* __restrict__ W, unsigned short* __restrict__ WT,
    int R, int C, int bx, int by, float (*t)[33])
{
  const int c0 = bx * 32, r0 = by * 32;
  const int x = threadIdx.x & 31, y = threadIdx.x >> 5;
#pragma unroll
  for (int i = 0; i < 4; ++i)
    t[y * 4 + i][x] = W[(size_t)(r0 + y * 4 + i) * C + c0 + x];
  __syncthreads();
#pragma unroll
  for (int i = 0; i < 4; ++i)
    WT[(size_t)(c0 + y * 4 + i) * R + r0 + x] = f2bf(t[x][y * 4 + i]);
}

__global__ __launch_bounds__(256) void prep_k(
    const float* __restrict__ hidden, const float* __restrict__ W_in,
    const float* __restrict__ W_dt, const float* __restrict__ W_out,
    unsigned short* __restrict__ Abf, unsigned short* __restrict__ WinT,
    unsigned short* __restrict__ WdtT, unsigned short* __restrict__ WoutT,
    float* __restrict__ outz, int* __restrict__ counters)
{
  __shared__ float t[32][33];
  const int bid = blockIdx.x;
  if (bid < 2048) {
    const int idx = bid * 256 + threadIdx.x;
    float4 v = ((const float4*)hidden)[idx];
    ushort4 o;
    o.x = f2bf(v.x); o.y = f2bf(v.y); o.z = f2bf(v.z); o.w = f2bf(v.w);
    ((ushort4*)Abf)[idx] = o;
  } else if (bid < 7232) {
    const int b = bid - 2048;
    tile_transpose(W_in, WinT, DM, DP, b % 162, b / 162, t);
  } else if (bid < 7360) {
    const int b = bid - 7232;
    tile_transpose(W_dt, WdtT, DTR, DI, b % 64, b / 64, t);
  } else if (bid < 9408) {
    const int b = bid - 7360;
    tile_transpose(W_out, WoutT, DI, DM, b % 32, b / 32, t);
  } else if (bid < 11456) {
    const int idx = (bid - 9408) * 256 + threadIdx.x;
    ((float4*)outz)[idx] = make_float4(0.f, 0.f, 0.f, 0.f);
  } else {
    if (threadIdx.x < 8) counters[threadIdx.x] = 0;
  }
}

// ---------------------------------------------------------------------------
// device-scope grid barrier (all NBLK blocks co-resident by construction)
// ---------------------------------------------------------------------------
__device__ __forceinline__ void grid_barrier(int* cnt) {
  __syncthreads();
  if (threadIdx.x == 0) {
    __threadfence();
    atomicAdd(cnt, 1);
    while (atomicAdd(cnt, 0) < NBLK) { __builtin_amdgcn_s_sleep(1); }
    __threadfence();
  }
  __syncthreads();
}

// ---------------------------------------------------------------------------
// megascan: conv + scan-pass1 + carry + scan-pass2 + gate in ONE kernel.
// block = (gb 0..7, s 0..63); thread owns (g_local, p) with 16 n-states in
// registers. LDS: sB 8K + sx 8K + sC 32K = 48K (sxr/raw-x staging aliases sC).
// ---------------------------------------------------------------------------
__global__ __launch_bounds__(256) void megascan(
    const float* __restrict__ zx, const unsigned short* __restrict__ deltabf,
    const float* __restrict__ A_log, const float* __restrict__ conv_w,
    const float* __restrict__ conv_b, const float* __restrict__ Dv,
    float* __restrict__ Sbuf, float* __restrict__ Hbuf,
    int* __restrict__ counters, unsigned short* __restrict__ ybuf)
{
  __shared__ __align__(16) float sB[SEGLEN][64];
  __shared__ __align__(16) float sx[SEGLEN][64];
  __shared__ __align__(16) float sC[SEGLEN][256];
  float* sxr = &sC[0][0];  // raw x staging [35][64], aliases sC (phase0 only)

  const int bid = blockIdx.x;
  const int gb = bid & 7, s = bid >> 3;
  const int tid = threadIdx.x;
  const int lg = tid >> 4, p = tid & 15;
  const int l0 = s * SEGLEN;

  // ---- phase 0: stage B + raw x; conv+silu -> sx ----
#pragma unroll
  for (int rep = 0; rep < 2; ++rep) {
    const int idx = rep * 256 + tid;
    const int i = idx >> 4, j4 = (idx & 15) << 2;
    gload16(&zx[(size_t)(l0 + i) * DP + OFF_B + gb * 64 + j4], (char*)&sB[0][0] + idx * 16);
  }
#pragma unroll
  for (int rep = 0; rep < 3; ++rep) {
    const int idx = rep * 256 + tid;
    if (idx < 560) {  // 35 rows x 16 float4
      const int j = idx >> 4, j4 = (idx & 15) << 2;
      int l = l0 + j - 3; if (l < 0) l = 0;
      gload16(&zx[(size_t)l * DP + OFF_X + gb * 64 + j4], (char*)sxr + idx * 16);
    }
  }
  const int cc_ = tid & 63, rr_ = tid >> 6;
  const float4 w4 = ((const float4*)conv_w)[gb * 64 + cc_];
  const float cbv = conv_b[gb * 64 + cc_];
  float An[16];
  {
    const float* ap = A_log + (size_t)gb * 4096 + tid * 16;
#pragma unroll
    for (int n = 0; n < 16; ++n) An[n] = -__expf(ap[n]);
  }
  __syncthreads();
  if (s == 0 && tid < 48) {  // zero the l<0 pad rows
    const int j = tid >> 4, c4 = (tid & 15) << 2;
#pragma unroll
    for (int k = 0; k < 4; ++k) sxr[j * 64 + c4 + k] = 0.f;
  }
  __syncthreads();
#pragma unroll
  for (int q = 0; q < 8; ++q) {
    const int i = rr_ * 8 + q;
    const float a = cbv + w4.x * sxr[i * 64 + cc_] + w4.y * sxr[(i + 1) * 64 + cc_]
                        + w4.z * sxr[(i + 2) * 64 + cc_] + w4.w * sxr[(i + 3) * 64 + cc_];
    sx[i][cc_] = siluf(a);
  }
  __syncthreads();

  // ---- phase 1: segment scan from h=0 -> (S, H_end) ----
  const unsigned short* dtp = deltabf + (size_t)l0 * DI + gb * 256 + tid;
  const int xj = ((lg >> 2) << 4) + p;
  const int bj = (lg >> 2) << 4;

  float h[16];
#pragma unroll
  for (int n = 0; n < 16; ++n) h[n] = 0.f;
  float S = 0.f;
  unsigned short dtc = dtp[0];
  for (int i = 0; i < SEGLEN; ++i) {
    const float dt = bf2f(dtc);
    if (i + 1 < SEGLEN) dtc = dtp[(size_t)(i + 1) * DI];
    S += dt;
    const float dtx = dt * sx[i][xj];
#pragma unroll
    for (int nq = 0; nq < 4; ++nq) {
      const float4 b4 = *(const float4*)&sB[i][bj + nq * 4];
      const float bb[4] = {b4.x, b4.y, b4.z, b4.w};
#pragma unroll
      for (int k = 0; k < 4; ++k) {
        const int n = nq * 4 + k;
        const float a = __expf(dt * An[n]);
        h[n] = fmaf(a, h[n], dtx * bb[k]);
      }
    }
  }
  Sbuf[(size_t)s * 2048 + gb * 256 + tid] = S;
  {
    float* hp = Hbuf + (size_t)s * 32768 + (size_t)gb * 4096 + tid * 16;
#pragma unroll
    for (int nq = 0; nq < 4; ++nq)
      *(float4*)(hp + nq * 4) =
          make_float4(h[nq * 4], h[nq * 4 + 1], h[nq * 4 + 2], h[nq * 4 + 3]);
  }

  grid_barrier(&counters[0]);

  // ---- phase 2: in-place exclusive carry over segments (blocks 0..127) ----
  if (bid < 128) {
    const int e = bid * 256 + tid;
    const float Ane = -__expf(A_log[e]);
    const int gp = e >> 4;
    float hc = 0.f;
    for (int s2 = 0; s2 < NSEG; ++s2) {
      const float tmp = Hbuf[(size_t)s2 * 32768 + e];
      Hbuf[(size_t)s2 * 32768 + e] = hc;  // carry INTO segment s2
      const float P = __expf(Ane * Sbuf[(size_t)s2 * 2048 + gp]);
      hc = fmaf(P, hc, tmp);
    }
  }

  grid_barrier(&counters[1]);

  // ---- phase 3: stage C, reload carry, rescan with y output ----
#pragma unroll
  for (int rep = 0; rep < 8; ++rep) {
    const int idx = rep * 256 + tid;
    const int i = idx >> 6, j4 = (idx & 63) << 2;
    gload16(&zx[(size_t)(l0 + i) * DP + OFF_C + gb * 256 + j4], (char*)&sC[0][0] + idx * 16);
  }
  {
    const float* hp = Hbuf + (size_t)s * 32768 + (size_t)gb * 4096 + tid * 16;
#pragma unroll
    for (int nq = 0; nq < 4; ++nq) {
      const float4 h4 = *(const float4*)(hp + nq * 4);
      h[nq * 4] = h4.x; h[nq * 4 + 1] = h4.y; h[nq * 4 + 2] = h4.z; h[nq * 4 + 3] = h4.w;
    }
  }
  const float Dd = Dv[gb * 256 + tid];
  __syncthreads();

  const float* zp = zx + (size_t)l0 * DP + OFF_Z + gb * 256 + tid;
  unsigned short* yp = ybuf + (size_t)l0 * DI + gb * 256 + tid;
  const int cj = lg << 4;

  dtc = dtp[0];
  float zc = zp[0];
  for (int i = 0; i < SEGLEN; ++i) {
    const float dt = bf2f(dtc), zv = zc;
    if (i + 1 < SEGLEN) {
      dtc = dtp[(size_t)(i + 1) * DI];
      zc  = zp[(size_t)(i + 1) * DP];
    }
    const float xv = sx[i][xj];
    const float dtx = dt * xv;
    float y = 0.f;
#pragma unroll
    for (int nq = 0; nq < 4; ++nq) {
      const float4 b4 = *(const float4*)&sB[i][bj + nq * 4];
      const float4 c4 = *(const float4*)&sC[i][cj + nq * 4];
      const float bb[4] = {b4.x, b4.y, b4.z, b4.w};
      const float cc[4] = {c4.x, c4.y, c4.z, c4.w};
#pragma unroll
      for (int k = 0; k < 4; ++k) {
        const int n = nq * 4 + k;
        const float a = __expf(dt * An[n]);
        h[n] = fmaf(a, h[n], dtx * bb[k]);
        y = fmaf(h[n], cc[k], y);
      }
    }
    yp[(size_t)i * DI] = f2bf((y + Dd * xv) * siluf(zv));
  }
}

// ---------------------------------------------------------------------------
extern "C" void kernel_launch(void* const* d_in, const int* in_sizes, int n_in,
                              void* d_out, int out_size, void* d_ws, size_t ws_size,
                              hipStream_t stream)
{
  const float* hidden  = (const float*)d_in[0];
  const float* W_in    = (const float*)d_in[1];
  const float* conv_w  = (const float*)d_in[2];
  const float* conv_b  = (const float*)d_in[3];
  const float* W_dt    = (const float*)d_in[4];
  const float* dt_bias = (const float*)d_in[5];
  const float* A_log   = (const float*)d_in[6];
  const float* Dvec    = (const float*)d_in[7];
  const float* W_out   = (const float*)d_in[8];
  float* out = (float*)d_out;

  // --- workspace layout (f32 offsets; lifetime-aliased; 78,774,528 B) ---
  float* ws = (float*)d_ws;
  float*          zx      = ws;                               // [0, 10,616,832)
  unsigned short* deltabf = (unsigned short*)(ws + 10616832); // 4,194,304 u16 -> ends f32 12,713,984
  float*          Sbuf    = ws + 12713984;                    // 131,072
  float*          Hbuf    = ws + 12845056;                    // 2,097,152 (ends 14,942,208)
  int*            counters= (int*)(ws + 14942208);            // 64 f32 slot
  unsigned short* Abf     = (unsigned short*)(ws + 14942272); // 2,097,152 u16 -> ends 15,990,848
  unsigned short* WinT    = (unsigned short*)(ws + 15990848); // 5,308,416 u16 -> ends 18,645,056
  unsigned short* WoutT   = (unsigned short*)(ws + 18645056); // 2,097,152 u16 -> ends 19,693,632
  // aliases (disjoint lifetimes):
  unsigned short* WdtT    = (unsigned short*)(ws + 12845056); // over Hbuf head (dead before megascan)
  unsigned short* dtrbf   = (unsigned short*)(ws + 12910592); // over Hbuf+64K (dead before megascan)
  unsigned short* Ybf     = (unsigned short*)(ws + 14942272); // over Abf+WinT (dead after in-proj)

  // 1. prep: casts + transposes + zero(out) + zero(counters)   [1 launch]
  prep_k<<<dim3(11457), 256, 0, stream>>>(hidden, W_in, W_dt, W_out,
                                          Abf, WinT, WdtT, WoutT, out, counters);

  // 2. in-proj (bf16 MFMA, dbuf) + dtr bf16 side-write         [1 launch]
  mfma_gemm<3><<<dim3(41, 16), 256, 0, stream>>>(
      Abf, WinT, zx, DP, DP, DM, DM / 32, nullptr, dtrbf);

  // 3. delta = softplus(dtr @ W_dt + 2*dt_bias) -> bf16        [1 launch]
  mfma_gemm<2><<<dim3(16, 16), 256, 0, stream>>>(
      dtrbf, WdtT, (float*)deltabf, DI, DI, DTR, DTR / 32, dt_bias, nullptr);

  // 4. megascan: conv + scan p1 + carry + p2 + gate -> Ybf     [1 launch]
  megascan<<<dim3(NBLK), 256, 0, stream>>>(zx, deltabf, A_log, conv_w, conv_b,
                                           Dvec, Sbuf, Hbuf, counters, Ybf);

  // 5. out-proj (bf16 MFMA, split-K=4 atomic on 8 MB output)   [1 launch]
  mfma_gemm<1><<<dim3(8, 16, 4), 256, 0, stream>>>(
      Ybf, WoutT, out, DM, DM, DI, DI / 4 / 32, nullptr, nullptr);
}

// Round 8
// 271.870 us; speedup vs baseline: 1.3852x; 1.3852x over previous
//
#include <hip/hip_runtime.h>
#include <hip/hip_bf16.h>
#include <cstdint>

// ---- problem dims ----
#define L_SEQ   2048
#define DM      1024   // d_model
#define DI      2048   // d_inner
#define DXB     512
#define DS      16     // d_state
#define DTR     64     // dt_rank
#define GH      128    // C-heads = DI/DS
#define DP      5184   // 2*DI + 2*DXB + DTR

// zxbcdt column offsets
#define OFF_Z   0
#define OFF_X   2048
#define OFF_B   2560
#define OFF_C   3072
#define OFF_DT  5120

// scan segmentation: 64 segments x 32 steps -> 512 blocks/scan kernel
#define NSEG    64
#define SEGLEN  32

typedef __bf16 bf16x8 __attribute__((ext_vector_type(8)));
typedef float  f32x4  __attribute__((ext_vector_type(4)));

__device__ __forceinline__ float siluf(float x) {
  return x / (1.f + __expf(-x));
}
__device__ __forceinline__ float softplusf(float x) {
  return x > 20.f ? x : log1pf(__expf(x));
}
__device__ __forceinline__ unsigned short f2bf(float f) {
  union { float f; unsigned u; } v; v.f = f;
  unsigned r = v.u + 0x7fffu + ((v.u >> 16) & 1u);
  return (unsigned short)(r >> 16);
}
__device__ __forceinline__ float bf2f(unsigned short u) {
  union { unsigned u; float f; } v; v.u = ((unsigned)u) << 16;
  return v.f;
}
// async global->LDS, 16B/lane. LDS dest must be wave-uniform base + lane*16.
__device__ __forceinline__ void gload16(const void* g, void* l) {
  __builtin_amdgcn_global_load_lds((const __attribute__((address_space(1))) void*)g,
                                   (__attribute__((address_space(3))) void*)l, 16, 0, 0);
}

// ---------------------------------------------------------------------------
// bf16 MFMA GEMM, 128x128 tile, 256 thr, 4 waves @ 64x64, double-buffered LDS.
// C[M,N](f32) (+)= A[M,K](bf16 row-major) * BT[N,K](bf16)^T
// MODE 0: plain store.
// MODE 1: atomicAdd (split-K via blockIdx.z; SMALL outputs only — R5 lesson).
// MODE 2: bf16 store of softplus(acc + 2*bias[col])   (delta GEMM)
// MODE 3: plain store + bf16 side-write of cols >= OFF_DT into aux (dtr slice)
// ---------------------------------------------------------------------------
template<int MODE>
__global__ __launch_bounds__(256) void mfma_gemm(
    const unsigned short* __restrict__ A,
    const unsigned short* __restrict__ BT,
    float* __restrict__ C, int ldc,
    int N, int K, int ktiles,
    const float* __restrict__ bias,
    unsigned short* __restrict__ aux)
{
  __shared__ __align__(16) unsigned short Asg[2][4096];
  __shared__ __align__(16) unsigned short Bsg[2][4096];

  const int tid  = threadIdx.x;
  const int wave = tid >> 6, lane = tid & 63;
  const int row0 = blockIdx.y * 128;
  const int col0 = blockIdx.x * 128;
  const int kbase = blockIdx.z * ktiles * 32;

  const int s0 = tid, s1 = tid + 256;
  const int rt0 = s0 >> 6, q0 = (s0 >> 4) & 3, m0 = s0 & 15;
  const int rt1 = s1 >> 6, q1 = (s1 >> 4) & 3, m1 = s1 & 15;
  const size_t aoff0 = (size_t)(row0 + rt0 * 16 + m0) * K + q0 * 8 + kbase;
  const size_t aoff1 = (size_t)(row0 + rt1 * 16 + m1) * K + q1 * 8 + kbase;
  int c0i = col0 + rt0 * 16 + m0; if (c0i > N - 1) c0i = N - 1;
  int c1i = col0 + rt1 * 16 + m1; if (c1i > N - 1) c1i = N - 1;
  const size_t boff0 = (size_t)c0i * K + q0 * 8 + kbase;
  const size_t boff1 = (size_t)c1i * K + q1 * 8 + kbase;

  f32x4 acc[4][4];
#pragma unroll
  for (int i = 0; i < 4; ++i)
#pragma unroll
    for (int j = 0; j < 4; ++j) acc[i][j] = (f32x4)0.f;

  const int warow = (wave >> 1) * 4;
  const int wacol = (wave & 1) * 4;

  gload16(A  + aoff0, Asg[0] + s0 * 8);
  gload16(A  + aoff1, Asg[0] + s0 * 8 + 2048);
  gload16(BT + boff0, Bsg[0] + s0 * 8);
  gload16(BT + boff1, Bsg[0] + s0 * 8 + 2048);

  for (int kt = 0; kt < ktiles; ++kt) {
    const int cur = kt & 1;
    __syncthreads();
    if (kt + 1 < ktiles) {
      const int k0 = (kt + 1) * 32;
      gload16(A  + aoff0 + k0, Asg[1 - cur] + s0 * 8);
      gload16(A  + aoff1 + k0, Asg[1 - cur] + s0 * 8 + 2048);
      gload16(BT + boff0 + k0, Bsg[1 - cur] + s0 * 8);
      gload16(BT + boff1 + k0, Bsg[1 - cur] + s0 * 8 + 2048);
    }

    bf16x8 af[4], bfr[4];
#pragma unroll
    for (int i = 0; i < 4; ++i)
      af[i] = *(const bf16x8*)(Asg[cur] + (warow + i) * 512 + lane * 8);
#pragma unroll
    for (int j = 0; j < 4; ++j)
      bfr[j] = *(const bf16x8*)(Bsg[cur] + (wacol + j) * 512 + lane * 8);
#pragma unroll
    for (int i = 0; i < 4; ++i)
#pragma unroll
      for (int j = 0; j < 4; ++j)
        acc[i][j] = __builtin_amdgcn_mfma_f32_16x16x32_bf16(af[i], bfr[j], acc[i][j], 0, 0, 0);
  }

  // epilogue: C/D layout col=lane&15, row=(lane>>4)*4+reg
#pragma unroll
  for (int i = 0; i < 4; ++i) {
    const int rbase = row0 + (warow + i) * 16 + ((lane >> 4) << 2);
#pragma unroll
    for (int j = 0; j < 4; ++j) {
      const int col = col0 + (wacol + j) * 16 + (lane & 15);
      if (col < N) {
#pragma unroll
        for (int r = 0; r < 4; ++r) {
          const float v = acc[i][j][r];
          if (MODE == 0 || MODE == 3) {
            C[(size_t)(rbase + r) * ldc + col] = v;
            if (MODE == 3 && col >= OFF_DT)
              aux[(size_t)(rbase + r) * DTR + (col - OFF_DT)] = f2bf(v);
          } else if (MODE == 1) {
            atomicAdd(C + (size_t)(rbase + r) * ldc + col, v);
          } else {  // MODE 2
            ((unsigned short*)C)[(size_t)(rbase + r) * ldc + col] =
                f2bf(softplusf(v + 2.f * bias[col]));
          }
        }
      }
    }
  }
}

// ---------------------------------------------------------------------------
// prep kernel: range-dispatched fusion of
//   [0,2048)      cast hidden -> Abf (bf16)
//   [2048,7232)   transpose+cast W_in (1024x5184) -> WinT (5184x1024)
//   [7232,7360)   transpose+cast W_dt (64x2048)   -> WdtT (2048x64)
//   [7360,9408)   transpose+cast W_out(2048x1024) -> WoutT(1024x2048)
//   [9408,11456)  zero out (for out-proj split-K atomics)
// ---------------------------------------------------------------------------
__device__ __forceinline__ void tile_transpose(
    const float* __restrict__ W, unsigned short* __restrict__ WT,
    int R, int C, int bx, int by, float (*t)[33])
{
  const int c0 = bx * 32, r0 = by * 32;
  const int x = threadIdx.x & 31, y = threadIdx.x >> 5;
#pragma unroll
  for (int i = 0; i < 4; ++i)
    t[y * 4 + i][x] = W[(size_t)(r0 + y * 4 + i) * C + c0 + x];
  __syncthreads();
#pragma unroll
  for (int i = 0; i < 4; ++i)
    WT[(size_t)(c0 + y * 4 + i) * R + r0 + x] = f2bf(t[x][y * 4 + i]);
}

__global__ __launch_bounds__(256) void prep_k(
    const float* __restrict__ hidden, const float* __restrict__ W_in,
    const float* __restrict__ W_dt, const float* __restrict__ W_out,
    unsigned short* __restrict__ Abf, unsigned short* __restrict__ WinT,
    unsigned short* __restrict__ WdtT, unsigned short* __restrict__ WoutT,
    float* __restrict__ outz)
{
  __shared__ float t[32][33];
  const int bid = blockIdx.x;
  if (bid < 2048) {
    const int idx = bid * 256 + threadIdx.x;
    float4 v = ((const float4*)hidden)[idx];
    ushort4 o;
    o.x = f2bf(v.x); o.y = f2bf(v.y); o.z = f2bf(v.z); o.w = f2bf(v.w);
    ((ushort4*)Abf)[idx] = o;
  } else if (bid < 7232) {
    const int b = bid - 2048;
    tile_transpose(W_in, WinT, DM, DP, b % 162, b / 162, t);
  } else if (bid < 7360) {
    const int b = bid - 7232;
    tile_transpose(W_dt, WdtT, DTR, DI, b % 64, b / 64, t);
  } else if (bid < 9408) {
    const int b = bid - 7360;
    tile_transpose(W_out, WoutT, DI, DM, b % 32, b / 32, t);
  } else {
    const int idx = (bid - 9408) * 256 + threadIdx.x;
    ((float4*)outz)[idx] = make_float4(0.f, 0.f, 0.f, 0.f);
  }
}

// ---------------------------------------------------------------------------
// Scan pass 1 (+fused conv): thread owns (g,p) with 16 n-states in registers.
// Stages raw x slice with 3-halo, computes conv+silu into sx in LDS.
// Outputs per segment: S (sum of dt) and segment-end state H (from h=0).
// ---------------------------------------------------------------------------
__global__ __launch_bounds__(256) void scan_p1(
    const float* __restrict__ zx, const unsigned short* __restrict__ deltabf,
    const float* __restrict__ A_log, const float* __restrict__ conv_w,
    const float* __restrict__ conv_b,
    float* __restrict__ Sout, float* __restrict__ Hout)
{
  const int gb = blockIdx.x, s = blockIdx.y;
  const int tid = threadIdx.x;
  const int lg = tid >> 4, p = tid & 15;
  const int l0 = s * SEGLEN;

  __shared__ __align__(16) float sB[SEGLEN][64];
  __shared__ __align__(16) float sx[SEGLEN][64];
  __shared__ __align__(16) float sxr[SEGLEN + 3][64];

#pragma unroll
  for (int rep = 0; rep < 2; ++rep) {
    const int idx = rep * 256 + tid;
    const int i = idx >> 4, j4 = (idx & 15) << 2;
    gload16(&zx[(size_t)(l0 + i) * DP + OFF_B + gb * 64 + j4], (char*)&sB[0][0] + idx * 16);
  }
#pragma unroll
  for (int rep = 0; rep < 3; ++rep) {
    const int idx = rep * 256 + tid;
    if (idx < 560) {  // 35 rows x 16 float4
      const int j = idx >> 4, j4 = (idx & 15) << 2;
      int l = l0 + j - 3; if (l < 0) l = 0;
      gload16(&zx[(size_t)l * DP + OFF_X + gb * 64 + j4], (char*)&sxr[0][0] + idx * 16);
    }
  }
  const int cc_ = tid & 63, rr_ = tid >> 6;
  const float4 w4 = ((const float4*)conv_w)[gb * 64 + cc_];
  const float cbv = conv_b[gb * 64 + cc_];
  float An[16];
  {
    const float* ap = A_log + (size_t)gb * 4096 + tid * 16;
#pragma unroll
    for (int n = 0; n < 16; ++n) An[n] = -__expf(ap[n]);
  }
  __syncthreads();
  if (s == 0 && tid < 48) {  // zero the l<0 halo rows
    const int j = tid >> 4, c4 = (tid & 15) << 2;
#pragma unroll
    for (int k = 0; k < 4; ++k) sxr[j][c4 + k] = 0.f;
  }
  __syncthreads();
#pragma unroll
  for (int q = 0; q < 8; ++q) {
    const int i = rr_ * 8 + q;
    const float a = cbv + w4.x * sxr[i][cc_] + w4.y * sxr[i + 1][cc_]
                        + w4.z * sxr[i + 2][cc_] + w4.w * sxr[i + 3][cc_];
    sx[i][cc_] = siluf(a);
  }
  __syncthreads();

  const unsigned short* dtp = deltabf + (size_t)l0 * DI + gb * 256 + tid;
  const int xj = ((lg >> 2) << 4) + p;
  const int bj = (lg >> 2) << 4;

  float h[16];
#pragma unroll
  for (int n = 0; n < 16; ++n) h[n] = 0.f;
  float S = 0.f;
  unsigned short dtc = dtp[0];
  for (int i = 0; i < SEGLEN; ++i) {
    const float dt = bf2f(dtc);
    if (i + 1 < SEGLEN) dtc = dtp[(size_t)(i + 1) * DI];
    S += dt;
    const float dtx = dt * sx[i][xj];
#pragma unroll
    for (int nq = 0; nq < 4; ++nq) {
      const float4 b4 = *(const float4*)&sB[i][bj + nq * 4];
      const float bb[4] = {b4.x, b4.y, b4.z, b4.w};
#pragma unroll
      for (int k = 0; k < 4; ++k) {
        const int n = nq * 4 + k;
        const float a = __expf(dt * An[n]);
        h[n] = fmaf(a, h[n], dtx * bb[k]);
      }
    }
  }

  Sout[(size_t)s * 2048 + gb * 256 + tid] = S;
  float* hp = Hout + (size_t)s * 32768 + (size_t)gb * 4096 + tid * 16;
#pragma unroll
  for (int nq = 0; nq < 4; ++nq)
    *(float4*)(hp + nq * 4) =
        make_float4(h[nq * 4], h[nq * 4 + 1], h[nq * 4 + 2], h[nq * 4 + 3]);
}

// ---------------------------------------------------------------------------
// Carry kernel: exclusive scan over segments per flat state e=(g,p,n).
// ---------------------------------------------------------------------------
__global__ __launch_bounds__(256) void scan_carry(
    const float* __restrict__ A_log, const float* __restrict__ Sin,
    const float* __restrict__ Hin, float* __restrict__ Hcarry)
{
  const int e = blockIdx.x * 256 + threadIdx.x;
  const float An = -__expf(A_log[e]);
  const int gp = e >> 4;
  float h = 0.f;
  for (int s = 0; s < NSEG; ++s) {
    Hcarry[(size_t)s * 32768 + e] = h;
    const float P = __expf(An * Sin[(size_t)s * 2048 + gp]);
    h = fmaf(P, h, Hin[(size_t)s * 32768 + e]);
  }
}

// ---------------------------------------------------------------------------
// Scan pass 2 (+fused conv): load carry, rerun segment, fused y/D/gate -> bf16.
// sxr staging aliases sC (disjoint lifetime: conv completes before sC staged).
// ---------------------------------------------------------------------------
__global__ __launch_bounds__(256) void scan_p2(
    const float* __restrict__ zx, const unsigned short* __restrict__ deltabf,
    const float* __restrict__ A_log, const float* __restrict__ conv_w,
    const float* __restrict__ conv_b, const float* __restrict__ Dv,
    const float* __restrict__ Hcarry, unsigned short* __restrict__ ybuf)
{
  const int gb = blockIdx.x, s = blockIdx.y;
  const int tid = threadIdx.x;
  const int lg = tid >> 4, p = tid & 15;
  const int l0 = s * SEGLEN;

  __shared__ __align__(16) float sC[SEGLEN][256];
  __shared__ __align__(16) float sB[SEGLEN][64];
  __shared__ __align__(16) float sx[SEGLEN][64];
  float* sxr = &sC[0][0];  // raw x staging [35][64], aliases sC (pre-conv only)

#pragma unroll
  for (int rep = 0; rep < 2; ++rep) {
    const int idx = rep * 256 + tid;
    const int i = idx >> 4, j4 = (idx & 15) << 2;
    gload16(&zx[(size_t)(l0 + i) * DP + OFF_B + gb * 64 + j4], (char*)&sB[0][0] + idx * 16);
  }
#pragma unroll
  for (int rep = 0; rep < 3; ++rep) {
    const int idx = rep * 256 + tid;
    if (idx < 560) {
      const int j = idx >> 4, j4 = (idx & 15) << 2;
      int l = l0 + j - 3; if (l < 0) l = 0;
      gload16(&zx[(size_t)l * DP + OFF_X + gb * 64 + j4], (char*)sxr + idx * 16);
    }
  }
  const int cc_ = tid & 63, rr_ = tid >> 6;
  const float4 w4 = ((const float4*)conv_w)[gb * 64 + cc_];
  const float cbv = conv_b[gb * 64 + cc_];
  float An[16], h[16];
  {
    const float* ap = A_log + (size_t)gb * 4096 + tid * 16;
#pragma unroll
    for (int n = 0; n < 16; ++n) An[n] = -__expf(ap[n]);
    const float* hp = Hcarry + (size_t)s * 32768 + (size_t)gb * 4096 + tid * 16;
#pragma unroll
    for (int nq = 0; nq < 4; ++nq) {
      const float4 h4 = *(const float4*)(hp + nq * 4);
      h[nq * 4] = h4.x; h[nq * 4 + 1] = h4.y; h[nq * 4 + 2] = h4.z; h[nq * 4 + 3] = h4.w;
    }
  }
  const float Dd = Dv[gb * 256 + tid];
  __syncthreads();
  if (s == 0 && tid < 48) {
    const int j = tid >> 4, c4 = (tid & 15) << 2;
#pragma unroll
    for (int k = 0; k < 4; ++k) sxr[j * 64 + c4 + k] = 0.f;
  }
  __syncthreads();
#pragma unroll
  for (int q = 0; q < 8; ++q) {
    const int i = rr_ * 8 + q;
    const float a = cbv + w4.x * sxr[i * 64 + cc_] + w4.y * sxr[(i + 1) * 64 + cc_]
                        + w4.z * sxr[(i + 2) * 64 + cc_] + w4.w * sxr[(i + 3) * 64 + cc_];
    sx[i][cc_] = siluf(a);
  }
  __syncthreads();  // conv done; sxr region now reusable as sC

#pragma unroll
  for (int rep = 0; rep < 8; ++rep) {
    const int idx = rep * 256 + tid;
    const int i = idx >> 6, j4 = (idx & 63) << 2;
    gload16(&zx[(size_t)(l0 + i) * DP + OFF_C + gb * 256 + j4], (char*)&sC[0][0] + idx * 16);
  }
  __syncthreads();

  const unsigned short* dtp = deltabf + (size_t)l0 * DI + gb * 256 + tid;
  const float* zp = zx + (size_t)l0 * DP + OFF_Z + gb * 256 + tid;
  unsigned short* yp = ybuf + (size_t)l0 * DI + gb * 256 + tid;
  const int xj = ((lg >> 2) << 4) + p;
  const int bj = (lg >> 2) << 4;
  const int cj = lg << 4;

  unsigned short dtc = dtp[0];
  float zc = zp[0];
  for (int i = 0; i < SEGLEN; ++i) {
    const float dt = bf2f(dtc), zv = zc;
    if (i + 1 < SEGLEN) {
      dtc = dtp[(size_t)(i + 1) * DI];
      zc  = zp[(size_t)(i + 1) * DP];
    }
    const float xv = sx[i][xj];
    const float dtx = dt * xv;
    float y = 0.f;
#pragma unroll
    for (int nq = 0; nq < 4; ++nq) {
      const float4 b4 = *(const float4*)&sB[i][bj + nq * 4];
      const float4 c4 = *(const float4*)&sC[i][cj + nq * 4];
      const float bb[4] = {b4.x, b4.y, b4.z, b4.w};
      const float cc[4] = {c4.x, c4.y, c4.z, c4.w};
#pragma unroll
      for (int k = 0; k < 4; ++k) {
        const int n = nq * 4 + k;
        const float a = __expf(dt * An[n]);
        h[n] = fmaf(a, h[n], dtx * bb[k]);
        y = fmaf(h[n], cc[k], y);
      }
    }
    yp[(size_t)i * DI] = f2bf((y + Dd * xv) * siluf(zv));
  }
}

// ---------------------------------------------------------------------------
extern "C" void kernel_launch(void* const* d_in, const int* in_sizes, int n_in,
                              void* d_out, int out_size, void* d_ws, size_t ws_size,
                              hipStream_t stream)
{
  const float* hidden  = (const float*)d_in[0];
  const float* W_in    = (const float*)d_in[1];
  const float* conv_w  = (const float*)d_in[2];
  const float* conv_b  = (const float*)d_in[3];
  const float* W_dt    = (const float*)d_in[4];
  const float* dt_bias = (const float*)d_in[5];
  const float* A_log   = (const float*)d_in[6];
  const float* Dvec    = (const float*)d_in[7];
  const float* W_out   = (const float*)d_in[8];
  float* out = (float*)d_out;

  // --- workspace layout (f32-word offsets; total 80,740,352 B == R3-proven) ---
  float* ws = (float*)d_ws;
  float*          zx      = ws;                               // [0, 10,616,832)
  unsigned short* deltabf = (unsigned short*)(ws + 10616832); // -> ends 12,713,984
  float*          Sbuf    = ws + 12713984;                    // -> 12,845,056
  float*          Hbuf    = ws + 12845056;                    // -> 14,942,208
  float*          Hcarry  = ws + 14942208;                    // -> 17,039,360
  unsigned short* WoutT   = (unsigned short*)(ws + 17039360); // -> 18,087,936
  unsigned short* Ybf     = (unsigned short*)(ws + 18087936); // -> 20,185,088
  // phase-A aliases (dead before their underlying regions are written):
  unsigned short* Abf   = (unsigned short*)(ws + 12845056);   // over Hbuf head; dead after in-proj
  unsigned short* WinT  = (unsigned short*)(ws + 13893632);   // over Hbuf tail+Hcarry head; dead after in-proj
  unsigned short* WdtT  = (unsigned short*)(ws + 16547840);   // over Hcarry; dead after delta-gemm
  unsigned short* dtrbf = (unsigned short*)(ws + 16613376);   // over Hcarry; dead after delta-gemm

  // 1. prep: cast + 3 transposes + zero(out)                    [1 launch]
  prep_k<<<dim3(11456), 256, 0, stream>>>(hidden, W_in, W_dt, W_out,
                                          Abf, WinT, WdtT, WoutT, out);

  // 2. in-proj (bf16 MFMA dbuf) + dtr bf16 side-write           [1 launch]
  mfma_gemm<3><<<dim3(41, 16), 256, 0, stream>>>(
      Abf, WinT, zx, DP, DP, DM, DM / 32, nullptr, dtrbf);

  // 3. delta = softplus(dtr @ W_dt + 2*dt_bias) -> bf16         [1 launch]
  mfma_gemm<2><<<dim3(16, 16), 256, 0, stream>>>(
      dtrbf, WdtT, (float*)deltabf, DI, DI, DTR, DTR / 32, dt_bias, nullptr);

  // 4. scan pass 1 (+conv): per-segment (S, H)                  [1 launch]
  scan_p1<<<dim3(8, NSEG), 256, 0, stream>>>(zx, deltabf, A_log, conv_w, conv_b,
                                             Sbuf, Hbuf);

  // 5. exclusive segment-carry scan                             [1 launch]
  scan_carry<<<dim3(128), 256, 0, stream>>>(A_log, Sbuf, Hbuf, Hcarry);

  // 6. scan pass 2 (+conv) -> y (bf16), fused D*x + silu(z)     [1 launch]
  scan_p2<<<dim3(8, NSEG), 256, 0, stream>>>(zx, deltabf, A_log, conv_w, conv_b,
                                             Dvec, Hcarry, Ybf);

  // 7. out-proj (bf16 MFMA dbuf, split-K=4 atomic, 8 MB out)    [1 launch]
  mfma_gemm<1><<<dim3(8, 16, 4), 256, 0, stream>>>(
      Ybf, WoutT, out, DM, DM, DI, DI / 4 / 32, nullptr, nullptr);
}